// Round 1
// 57499.750 us; speedup vs baseline: 1.8006x; 1.8006x over previous
//
#include <hip/hip_runtime.h>
#include <hip/hip_bf16.h>
#include <math.h>

// BottomLevelDecoderRNN: B=256, BARS=16, CH=512, H=1024, V=130, T=256
#define B_    256
#define BARS_ 16
#define CH_   512
#define H_    1024
#define V_    130
#define T_    256
#define G4_   4096
#define G3_   3072            // compact 3-gate stride (f gate dead)
#define BH_   (B_ * H_)       // 262144
#define BG3_  (B_ * G3_)      // 786432

typedef __hip_bfloat16 bf16;
typedef short s16x8 __attribute__((ext_vector_type(8)));
typedef float f32x4 __attribute__((ext_vector_type(4)));

#define MAXZ 7

// Fused bf16-MFMA gemm, fully per-z parameterized.
// mode 0: fp32 store (+bias); mode 1: LSTM act -> bf16 (NG==3 only);
// mode 2: tanh -> bf16; mode 3: tanh -> 7-way reset broadcast (h1x3,h2x3,ctx)
struct MP {
  const bf16* A0[MAXZ]; const bf16* A0b[MAXZ]; const bf16* W0[MAXZ];
  const float* base0[MAXZ]; const int* gidx[MAXZ];
  const float* base1[MAXZ]; const float* base2[MAXZ];
  const float* bias[MAXZ];
  float* Cf[MAXZ]; bf16* Ch[MAXZ];
  int lda[MAXZ], ldw[MAXZ], K[MAXZ], Nc[MAXZ], ldc[MAXZ], mode[MAXZ];
  int gW[MAXZ][3];   // weight-row / bias offsets (original 4xH layout)
  int gC[MAXZ][3];   // partial-buffer column offsets (compact 3xH layout)
  int M, gstride;
};

__device__ __forceinline__ float sigf(float x) { return 1.f / (1.f + __expf(-x)); }
__device__ __forceinline__ float tanhfa(float x) { return 2.f / (1.f + __expf(-2.f * x)) - 1.f; }

template<int NG>
__global__ __launch_bounds__(256) void mfma_gemm(MP p) {
  const int z   = blockIdx.z;
  const int n0  = blockIdx.x * 64;
  const int Ncz = p.Nc[z];
  if (n0 >= Ncz) return;                 // uniform early-out (merged out-gemm z's)
  const int m0  = blockIdx.y * 64;
  const int tid = threadIdx.x;
  const int lane = tid & 63;
  const int wv   = tid >> 6;
  const int srow = tid >> 2;             // staging row 0..63
  const int scol = (tid & 3) << 4;       // staging col 0/16/32/48

  __shared__ bf16 As[64][72];            // +8 pad: 2-way LDS aliasing only (free)
  __shared__ bf16 Ws[NG][64][72];

  const bf16* A  = p.A0[z];
  const bf16* Ab = p.A0b[z];
  const bf16* W  = p.W0[z];
  const int lda = p.lda[z], ldw = p.ldw[z], K = p.K[z];

  const bool aok = (m0 + srow) < p.M;
  const bf16* ap  = A + (long)(m0 + srow) * lda + scol;
  const bf16* abp = Ab ? Ab + (long)(m0 + srow) * lda + scol : nullptr;
  const int wr = n0 + srow;
  const bool wok = wr < Ncz;
  const bf16* wp[NG];
#pragma unroll
  for (int g = 0; g < NG; ++g)
    wp[g] = W + (long)(p.gW[z][g] + wr) * ldw + scol;

  f32x4 acc[NG][4];
#pragma unroll
  for (int g = 0; g < NG; ++g)
#pragma unroll
    for (int mf = 0; mf < 4; ++mf) acc[g][mf] = (f32x4){0.f, 0.f, 0.f, 0.f};

  bf16 areg[16], breg[16], wreg[NG][16];
  auto PF = [&](int k0) {                // issue global loads for tile k0
    if (aok) {
      *(float4*)(areg)     = *(const float4*)(ap + k0);
      *(float4*)(areg + 8) = *(const float4*)(ap + k0 + 8);
      if (abp) {
        *(float4*)(breg)     = *(const float4*)(abp + k0);
        *(float4*)(breg + 8) = *(const float4*)(abp + k0 + 8);
      }
    } else {
#pragma unroll
      for (int q = 0; q < 16; ++q) areg[q] = __float2bfloat16(0.f);
    }
#pragma unroll
    for (int g = 0; g < NG; ++g) {
      if (wok) {
        *(float4*)(wreg[g])     = *(const float4*)(wp[g] + k0);
        *(float4*)(wreg[g] + 8) = *(const float4*)(wp[g] + k0 + 8);
      } else {
#pragma unroll
        for (int q = 0; q < 16; ++q) wreg[g][q] = __float2bfloat16(0.f);
      }
    }
  };

  PF(0);
  for (int k0 = 0; k0 < K; k0 += 64) {
    if (abp && aok) {                    // A0b element-add (out gemm)
#pragma unroll
      for (int q = 0; q < 16; ++q)
        areg[q] = __float2bfloat16(__bfloat162float(areg[q]) + __bfloat162float(breg[q]));
    }
    __syncthreads();                     // prev-iter LDS reads complete
    *(float4*)&As[srow][scol]     = *(float4*)(areg);
    *(float4*)&As[srow][scol + 8] = *(float4*)(areg + 8);
#pragma unroll
    for (int g = 0; g < NG; ++g) {
      *(float4*)&Ws[g][srow][scol]     = *(float4*)(wreg[g]);
      *(float4*)&Ws[g][srow][scol + 8] = *(float4*)(wreg[g] + 8);
    }
    __syncthreads();
    if (k0 + 64 < K) PF(k0 + 64);        // prefetch next tile; latency hides under MFMAs
#pragma unroll
    for (int kc = 0; kc < 2; ++kc) {
      const int ko = kc * 32 + ((lane >> 4) << 3);
      s16x8 bfr[NG];
#pragma unroll
      for (int g = 0; g < NG; ++g)
        bfr[g] = *(const s16x8*)&Ws[g][(wv << 4) + (lane & 15)][ko];
#pragma unroll
      for (int mf = 0; mf < 4; ++mf) {
        s16x8 afr = *(const s16x8*)&As[(mf << 4) + (lane & 15)][ko];
#pragma unroll
        for (int g = 0; g < NG; ++g)
          acc[g][mf] = __builtin_amdgcn_mfma_f32_16x16x32_bf16(afr, bfr[g], acc[g][mf], 0, 0, 0);
      }
    }
  }

  // epilogue — C/D layout: col=lane&15, row=(lane>>4)*4+reg  [m89-verified]
  const int colg = n0 + (wv << 4) + (lane & 15);
  if (colg >= Ncz) return;
  const int mode = p.mode[z];
  const int ldcz = p.ldc[z];
  const float* bs = p.bias[z];

  if (mode == 0) {
    float* C = p.Cf[z];
#pragma unroll
    for (int mf = 0; mf < 4; ++mf)
#pragma unroll
      for (int r = 0; r < 4; ++r) {
        const int row = m0 + (mf << 4) + ((lane >> 4) << 2) + r;
        if (row >= p.M) continue;
#pragma unroll
        for (int g = 0; g < NG; ++g) {
          float v = acc[g][mf][r];
          if (bs) v += bs[p.gW[z][g] + colg];
          C[(long)row * ldcz + p.gC[z][g] + colg] = v;
        }
      }
  } else if (mode == 1) {
    if constexpr (NG == 3) {
      bf16* Ch = p.Ch[z];
      const float* b0 = p.base0[z]; const int* gx = p.gidx[z];
      const float* b1 = p.base1[z]; const float* b2 = p.base2[z];
      const int gw0 = p.gW[z][0], gw1 = p.gW[z][1], gw2 = p.gW[z][2];
      const int gc0 = p.gC[z][0], gc1 = p.gC[z][1], gc2 = p.gC[z][2];
#pragma unroll
      for (int mf = 0; mf < 4; ++mf)
#pragma unroll
        for (int r = 0; r < 4; ++r) {
          const int row = m0 + (mf << 4) + ((lane >> 4) << 2) + r;
          if (row >= p.M) continue;
          float gi = acc[0][mf][r], gg = acc[1][mf][r], go = acc[2][mf][r];
          if (b0) {
            long r0 = gx ? (long)gx[(long)row * p.gstride] : (long)row;
            const float* q = b0 + r0 * (long)G3_;
            gi += q[gc0 + colg]; gg += q[gc1 + colg]; go += q[gc2 + colg];
          }
          if (b1) { const float* q = b1 + (long)row * G3_;
            gi += q[gc0 + colg]; gg += q[gc1 + colg]; go += q[gc2 + colg]; }
          if (b2) { const float* q = b2 + (long)row * G3_;
            gi += q[gc0 + colg]; gg += q[gc1 + colg]; go += q[gc2 + colg]; }
          if (bs) { gi += bs[gw0 + colg]; gg += bs[gw1 + colg]; go += bs[gw2 + colg]; }
          float h = sigf(go) * tanhfa(sigf(gi) * tanhfa(gg));
          Ch[(long)row * ldcz + colg] = __float2bfloat16(h);
        }
    }
  } else if (mode == 2) {
    bf16* Ch = p.Ch[z];
#pragma unroll
    for (int mf = 0; mf < 4; ++mf)
#pragma unroll
      for (int r = 0; r < 4; ++r) {
        const int row = m0 + (mf << 4) + ((lane >> 4) << 2) + r;
        if (row >= p.M) continue;
        float v = acc[0][mf][r];
        if (bs) v += bs[p.gW[z][0] + colg];
        Ch[(long)row * ldcz + colg] = __float2bfloat16(tanhfa(v));
      }
  } else { // mode 3: tanh + reset broadcast to h1(x3), h2(x3), ctx
    bf16* d1 = p.Ch[z];
    bf16* d2 = (bf16*)(void*)p.Cf[z];
    bf16* dc = (bf16*)(void*)p.base0[z];
#pragma unroll
    for (int mf = 0; mf < 4; ++mf)
#pragma unroll
      for (int r = 0; r < 4; ++r) {
        const int row = m0 + (mf << 4) + ((lane >> 4) << 2) + r;
        if (row >= p.M) continue;
        float v = acc[0][mf][r];
        if (bs) v += bs[colg];
        const bf16 bv = __float2bfloat16(tanhfa(v));
        const long idx = (long)row * ldcz + colg;
        d1[idx] = bv; d1[idx + BH_] = bv; d1[idx + 2L * BH_] = bv;
        d2[idx] = bv; d2[idx + BH_] = bv; d2[idx + 2L * BH_] = bv;
        dc[idx] = bv;
      }
  }
}

__global__ __launch_bounds__(256) void conv_k(const float* s, bf16* d, long n4) {
  long i = (long)blockIdx.x * 256 + threadIdx.x;
  if (i >= n4) return;
  float4 v = ((const float4*)s)[i];
  d[4 * i]     = __float2bfloat16(v.x);
  d[4 * i + 1] = __float2bfloat16(v.y);
  d[4 * i + 2] = __float2bfloat16(v.z);
  d[4 * i + 3] = __float2bfloat16(v.w);
}

__global__ __launch_bounds__(256) void x1cat_k(const float* emb, const float* c, int bar, bf16* x1) {
  const long idx = (long)blockIdx.x * 256 + threadIdx.x;  // < 3*B*1024
  const int i = (int)(idx >> 18);
  const int r = (int)(idx & 262143);
  const int b = r >> 10;
  const int k = r & 1023;
  float v;
  if (k < CH_) v = emb[(long)i * V_ * CH_ + k];
  else         v = c[(long)b * BARS_ * CH_ + (long)bar * CH_ + (k - CH_)];
  x1[idx] = __float2bfloat16(v);
}

extern "C" void kernel_launch(void* const* d_in, const int* in_sizes, int n_in,
                              void* d_out, int out_size, void* d_ws, size_t ws_size,
                              hipStream_t stream) {
  const float* c     = (const float*)d_in[0];
  const float* l1Wih = (const float*)d_in[1];
  const float* l1Whh = (const float*)d_in[2];
  const float* l1b   = (const float*)d_in[3];
  const float* cWih  = (const float*)d_in[4];
  const float* cWhh  = (const float*)d_in[5];
  const float* cb    = (const float*)d_in[6];
  const float* l2Wih = (const float*)d_in[7];
  const float* l2Whh = (const float*)d_in[8];
  const float* l2b   = (const float*)d_in[9];
  const float* outW  = (const float*)d_in[10];
  const float* outb  = (const float*)d_in[11];
  const float* hidW  = (const float*)d_in[12];
  const float* hidb  = (const float*)d_in[13];
  const float* emb   = (const float*)d_in[14];
  const int*   target = (const int*)d_in[15];
  float* out = (float*)d_out;

  // ---- workspace carve (compact 3-gate fp32 buffers; 16B-aligned) ----
  char* wp = (char*)d_ws;
  auto cf = [&](long n) { float* r = (float*)wp; wp += n * sizeof(float); return r; };
  auto ch = [&](long n) { bf16*  r = (bf16*)wp;  wp += n * sizeof(bf16);  return r; };
  float* embW = cf(3L * V_ * G3_);
  float* xW1  = cf(3L * BG3_);
  float* cW2  = cf(3L * BG3_);
  float* cWu  = cf(1L * BG3_);
  float* Pb   = cf(3L * BG3_);
  float* Pp   = cf(2L * BG3_);
  float* W2h  = cf(3L * BG3_);
  bf16* l1Wih_h = ch(3L * G4_ * 1024);
  bf16* l1Whh_h = ch(3L * G4_ * 1024);
  bf16* cWih_h  = ch((long)G4_ * 3072);
  bf16* cWhh_h  = ch((long)G4_ * 1024);
  bf16* l2Wih_h = ch(3L * G4_ * 1536);
  bf16* l2Whh_h = ch(3L * G4_ * 1024);
  bf16* outW_h  = ch(3L * V_ * 1024);
  bf16* hidW_h  = ch(1024L * 512);
  bf16* emb_h   = ch(3L * V_ * CH_);
  bf16* c_h     = ch((long)B_ * BARS_ * CH_);
  bf16* x1_h    = ch(3L * B_ * 1024);
  bf16* h1buf[2] = { ch(3L * BH_), ch(3L * BH_) };
  bf16* h2buf[2] = { ch(3L * BH_), ch(3L * BH_) };
  bf16* ctxbuf[2] = { ch((long)BH_), ch((long)BH_) };
  bf16* unew = ch(2L * BH_);

  auto conv = [&](const float* s, bf16* d, long n) {
    long n4 = n / 4;
    conv_k<<<dim3((unsigned)((n4 + 255) / 256)), dim3(256), 0, stream>>>(s, d, n4);
  };
  conv(l1Wih, l1Wih_h, 3L * G4_ * 1024);
  conv(l1Whh, l1Whh_h, 3L * G4_ * 1024);
  conv(cWih,  cWih_h,  (long)G4_ * 3072);
  conv(cWhh,  cWhh_h,  (long)G4_ * 1024);
  conv(l2Wih, l2Wih_h, 3L * G4_ * 1536);
  conv(l2Whh, l2Whh_h, 3L * G4_ * 1024);
  conv(outW,  outW_h,  3L * V_ * 1024);
  conv(hidW,  hidW_h,  1024L * 512);
  conv(emb,   emb_h,   3L * V_ * CH_);
  conv(c,     c_h,     (long)B_ * BARS_ * CH_);

  const int GW[3] = { 0, 2048, 3072 };   // i, g, o rows (f gate dead)
  const int GC[3] = { 0, 1024, 2048 };   // compact partial columns

  auto Zs = [&](MP& p, int z, const bf16* A, int lda, const bf16* W, int ldw, int K,
                int mode, int Nc, int ldc, bool stdg) {
    p.A0[z] = A; p.lda[z] = lda; p.W0[z] = W; p.ldw[z] = ldw; p.K[z] = K;
    p.mode[z] = mode; p.Nc[z] = Nc; p.ldc[z] = ldc;
    for (int g = 0; g < 3; ++g) { p.gW[z][g] = stdg ? GW[g] : 0; p.gC[z][g] = stdg ? GC[g] : 0; }
  };

  { // embW[i] = emb[i] @ l1Wih[1][:, :512]^T  (once; bias folded into cWu)
    MP p{}; p.M = V_;
    for (int z = 0; z < 3; ++z) {
      Zs(p, z, emb_h + (long)z * V_ * CH_, CH_, l1Wih_h + (long)G4_ * 1024, 1024, CH_, 0, H_, G3_, true);
      p.Cf[z] = embW + (long)z * V_ * G3_;
    }
    mfma_gemm<3><<<dim3(16, 3, 3), dim3(256), 0, stream>>>(p);
  }

  for (int t = 0; t < T_; ++t) {
    const int bar = t >> 4;
    const int rb = t & 1, wb = rb ^ 1;
    bf16* h1r = h1buf[rb]; bf16* h1w = h1buf[wb];
    bf16* h2r = h2buf[rb]; bf16* h2w = h2buf[wb];

    if ((t & 15) == 0) {
      const int prev = bar ? bar - 1 : 0;
      { // fused Hbar+reset: tanh(c[:,prev,:] @ hidW^T + hidb) broadcast to h1/h2/ctx
        MP p{}; p.M = B_;
        Zs(p, 0, c_h + (long)prev * CH_, BARS_ * CH_, hidW_h, CH_, CH_, 3, H_, H_, false);
        p.bias[0] = hidb;
        p.Ch[0] = h1buf[rb]; p.Cf[0] = (float*)h2buf[rb]; p.base0[0] = (const float*)ctxbuf[rb];
        mfma_gemm<1><<<dim3(16, 4, 1), dim3(256), 0, stream>>>(p);
      }
      x1cat_k<<<dim3(3 * BH_ / 256), dim3(256), 0, stream>>>(emb, c, bar, x1_h);
      { // merged per-bar: xW1 (3z, K=1024) + cW2 (3z, K=512) + cWu (1z, K=512)
        MP p{}; p.M = B_;
        for (int z = 0; z < 3; ++z) {
          Zs(p, z, x1_h + (long)z * B_ * 1024, 1024, l1Wih_h + (long)z * G4_ * 1024, 1024, 1024, 0, H_, G3_, true);
          p.bias[z] = l1b + (long)z * G4_; p.Cf[z] = xW1 + (long)z * BG3_;
        }
        for (int i = 0; i < 3; ++i) {
          const int z = 3 + i;
          Zs(p, z, c_h + (long)bar * CH_, BARS_ * CH_, l2Wih_h + (long)i * G4_ * 1536 + 1024, 1536, CH_, 0, H_, G3_, true);
          p.bias[z] = l2b + (long)i * G4_; p.Cf[z] = cW2 + (long)i * BG3_;
        }
        Zs(p, 6, c_h + (long)bar * CH_, BARS_ * CH_, l1Wih_h + (long)G4_ * 1024 + 512, 1024, CH_, 0, H_, G3_, true);
        p.bias[6] = l1b + G4_; p.Cf[6] = cWu;
        mfma_gemm<3><<<dim3(16, 4, 7), dim3(256), 0, stream>>>(p);
      }
    }

    // D1: h1 (3z, MODE1) + W2h[i] = h2r[i] @ l2Whh[i]^T (3z, MODE0, hoisted off chain)
    { MP p{}; p.M = B_;
      for (int z = 0; z < 3; ++z) {
        Zs(p, z, h1r + (long)z * BH_, H_, l1Whh_h + (long)z * G4_ * 1024, H_, H_, 1, H_, H_, true);
        p.base0[z] = xW1 + (long)z * BG3_; p.Ch[z] = h1w + (long)z * BH_;
      }
      for (int i = 0; i < 3; ++i) {
        const int z = 3 + i;
        Zs(p, z, h2r + (long)i * BH_, H_, l2Whh_h + (long)i * G4_ * 1024, H_, H_, 0, H_, G3_, true);
        p.Cf[z] = W2h + (long)i * BG3_;
      }
      mfma_gemm<3><<<dim3(16, 4, 6), dim3(256), 0, stream>>>(p);
    }
    // D2: unew (2z, MODE1, embW gather + cWu) + Pb[i] = h1w[i] @ cWih[:, i*1024:]^T (3z)
    { MP p{}; p.M = B_; p.gstride = T_;
      for (int z = 0; z < 2; ++z) {
        Zs(p, z, h1w + (long)z * BH_, H_, l1Whh_h + (long)G4_ * 1024, H_, H_, 1, H_, H_, true);
        p.base0[z] = embW + (long)z * V_ * G3_; p.gidx[z] = target + (long)z * B_ * T_ + t;
        p.base1[z] = cWu; p.Ch[z] = unew + (long)z * BH_;
      }
      for (int i = 0; i < 3; ++i) {
        const int z = 2 + i;
        Zs(p, z, h1w + (long)i * BH_, H_, cWih_h + (long)i * 1024, 3072, H_, 0, H_, G3_, true);
        p.Cf[z] = Pb + (long)i * BG3_;
      }
      mfma_gemm<3><<<dim3(16, 4, 5), dim3(256), 0, stream>>>(p);
    }
    const int cc = t & 1;   // ctx ping-pong parity
    // D3: Pu (2z) + ctx0 (1z)
    { MP p{}; p.M = B_;
      for (int z = 0; z < 2; ++z) {
        Zs(p, z, unew + (long)z * BH_, H_, cWih_h + (long)z * 1024, 3072, H_, 0, H_, G3_, true);
        p.Cf[z] = Pp + (long)z * BG3_;
      }
      Zs(p, 2, ctxbuf[cc], H_, cWhh_h, H_, H_, 1, H_, H_, true);
      p.base0[2] = Pb; p.base1[2] = Pb + BG3_; p.base2[2] = Pb + 2L * BG3_;
      p.bias[2] = cb; p.Ch[2] = ctxbuf[cc ^ 1];
      mfma_gemm<3><<<dim3(16, 4, 3), dim3(256), 0, stream>>>(p);
    }
    // D4: h2_0 + ctx1  (both read ctxbuf[cc^1])
    { MP p{}; p.M = B_;
      Zs(p, 0, ctxbuf[cc ^ 1], H_, l2Wih_h, 1536, H_, 1, H_, H_, true);
      p.base0[0] = cW2; p.base1[0] = W2h; p.Ch[0] = h2w;
      Zs(p, 1, ctxbuf[cc ^ 1], H_, cWhh_h, H_, H_, 1, H_, H_, true);
      p.base0[1] = Pp; p.base1[1] = Pb + BG3_; p.base2[1] = Pb + 2L * BG3_;
      p.bias[1] = cb; p.Ch[1] = ctxbuf[cc];
      mfma_gemm<3><<<dim3(16, 4, 2), dim3(256), 0, stream>>>(p);
    }
    // D5: h2_1 + ctx2 + out0
    { MP p{}; p.M = B_;
      Zs(p, 0, ctxbuf[cc], H_, l2Wih_h + (long)1 * G4_ * 1536, 1536, H_, 1, H_, H_, true);
      p.base0[0] = cW2 + BG3_; p.base1[0] = W2h + BG3_; p.Ch[0] = h2w + BH_;
      Zs(p, 1, ctxbuf[cc], H_, cWhh_h, H_, H_, 1, H_, H_, true);
      p.base0[1] = Pp; p.base1[1] = Pp + BG3_; p.base2[1] = Pb + 2L * BG3_;
      p.bias[1] = cb; p.Ch[1] = ctxbuf[cc ^ 1];
      Zs(p, 2, h1w, H_, outW_h, H_, H_, 0, V_, T_ * V_, false);
      p.A0b[2] = h2w; p.bias[2] = outb; p.Cf[2] = out + (long)t * V_;
      mfma_gemm<3><<<dim3(16, 4, 3), dim3(256), 0, stream>>>(p);
    }
    // D6: h2_2 + out1
    { MP p{}; p.M = B_;
      Zs(p, 0, ctxbuf[cc ^ 1], H_, l2Wih_h + (long)2 * G4_ * 1536, 1536, H_, 1, H_, H_, true);
      p.base0[0] = cW2 + 2L * BG3_; p.base1[0] = W2h + 2L * BG3_; p.Ch[0] = h2w + 2L * BH_;
      Zs(p, 1, h1w + BH_, H_, outW_h + (long)V_ * H_, H_, H_, 0, V_, T_ * V_, false);
      p.A0b[1] = h2w + BH_; p.bias[1] = outb + V_; p.Cf[1] = out + (long)B_ * T_ * V_ + (long)t * V_;
      mfma_gemm<3><<<dim3(16, 4, 2), dim3(256), 0, stream>>>(p);
    }
    // D7: out2
    { MP p{}; p.M = B_;
      Zs(p, 0, h1w + 2L * BH_, H_, outW_h + 2L * V_ * H_, H_, H_, 0, V_, T_ * V_, false);
      p.A0b[0] = h2w + 2L * BH_; p.bias[0] = outb + 2 * V_;
      p.Cf[0] = out + 2L * B_ * T_ * V_ + (long)t * V_;
      mfma_gemm<1><<<dim3(3, 4, 1), dim3(256), 0, stream>>>(p);
    }
  }
}